// Round 7
// baseline (536.287 us; speedup 1.0000x reference)
//
#include <hip/hip_runtime.h>
#include <hip/hip_bf16.h>

#define TN 131072      // total nodes (B*N)
#define NB 256         // batches
#define NN 512         // nodes per batch
#define FD 128         // per-layer feature dim
#define DD 512         // concat dim
#define NE 2097152     // edges
#define NL 4           // layers
#define HPITCH 128     // hW row pitch (shorts) — unpadded, gather reads full rows
#define APITCH 136     // agg tile pitch (shorts)

typedef __attribute__((ext_vector_type(8))) short bf16x8;
typedef __attribute__((ext_vector_type(4))) float f32x4;

__device__ __forceinline__ float b2f(unsigned int u) {
    union { unsigned int i; float f; } c; c.i = u << 16; return c.f;
}
__device__ __forceinline__ unsigned short f2b(float f) {
    union { float f; unsigned int i; } c; c.f = f;
    unsigned int x = c.i;
    return (unsigned short)((x + 0x7fffu + ((x >> 16) & 1u)) >> 16);  // RNE
}
// unpack a bf16 pair from one dword, add into two fp32 accs (4 VALU total)
__device__ __forceinline__ void add2(float& a0, float& a1, unsigned int v) {
    union { unsigned int u; float f; } lo, hi;
    lo.u = v << 16; hi.u = v & 0xffff0000u;
    a0 += lo.f; a1 += hi.f;
}
__device__ __forceinline__ uint4 packv8(const float* a) {
    uint4 p;
    p.x = (unsigned int)f2b(a[0]) | ((unsigned int)f2b(a[1]) << 16);
    p.y = (unsigned int)f2b(a[2]) | ((unsigned int)f2b(a[3]) << 16);
    p.z = (unsigned int)f2b(a[4]) | ((unsigned int)f2b(a[5]) << 16);
    p.w = (unsigned int)f2b(a[6]) | ((unsigned int)f2b(a[7]) << 16);
    return p;
}
// fast tanh: (e^{2x}-1)/(e^{2x}+1), clamped
__device__ __forceinline__ float ftanh(float x) {
    float xc = fminf(fmaxf(x, -9.0f), 9.0f);
    float e = __expf(2.0f * xc);
    return (e - 1.0f) * __builtin_amdgcn_rcpf(e + 1.0f);
}

// ---------------- CSR build ----------------
__global__ void count_k(const int* __restrict__ dst, int* __restrict__ counts) {
    int e = blockIdx.x * blockDim.x + threadIdx.x;
    if (e < NE) atomicAdd(&counts[dst[e]], 1);
}

__global__ __launch_bounds__(512) void scan_b_k(const int* __restrict__ counts,
                                                int* __restrict__ row_ptr,
                                                int* __restrict__ cursor,
                                                float* __restrict__ degs) {
    __shared__ int ss[512];
    int b = blockIdx.x, t = threadIdx.x;
    int gid = b * NN + t;
    int c = counts[gid];
    ss[t] = c;
    __syncthreads();
    for (int off = 1; off < 512; off <<= 1) {
        int v = (t >= off) ? ss[t - off] : 0;
        __syncthreads();
        ss[t] += v;
        __syncthreads();
    }
    int excl = ss[t] - c;
    int base = b * (NN * 16) + excl;   // DEG=16
    row_ptr[gid] = base;
    cursor[gid]  = base;
    degs[gid]    = (float)(c + 1);
    if (b == NB - 1 && t == NN - 1) row_ptr[TN] = NE;
}

__global__ void fill_k(const int* __restrict__ src, const int* __restrict__ dst,
                       int* __restrict__ cursor, int* __restrict__ col_idx) {
    int e = blockIdx.x * blockDim.x + threadIdx.x;
    if (e < NE) {
        int p = atomicAdd(&cursor[dst[e]], 1);
        col_idx[p] = src[e];
    }
}

// ---------------- att_W transpose + bf16 cast:  Wt[n][k] = bf16(W[k][n]) ----------------
__global__ __launch_bounds__(256) void transpose_cast_k(const float* __restrict__ W,
                                                        unsigned short* __restrict__ Wt) {
    __shared__ float tile[32][33];
    int k0 = blockIdx.x * 32, n0 = blockIdx.y * 32;
    int tx = threadIdx.x & 31, ty = threadIdx.x >> 5;  // 32 x 8
    #pragma unroll
    for (int i = 0; i < 32; i += 8)
        tile[ty + i][tx] = W[(size_t)(k0 + ty + i) * DD + n0 + tx];
    __syncthreads();
    #pragma unroll
    for (int i = 0; i < 32; i += 8)
        Wt[(size_t)(n0 + ty + i) * DD + k0 + tx] = f2b(tile[tx][ty + i]);
}

// ---------------- conv_W transpose + bf16 cast per layer: Wt_l[o][f] = bf16(W_l[f][o]) ----
__global__ __launch_bounds__(256) void transp_convW_k(const float* __restrict__ W,
                                                      unsigned short* __restrict__ Wt) {
    __shared__ float tile[32][33];
    const float* Wl = W + (size_t)blockIdx.z * FD * FD;
    unsigned short* Wtl = Wt + (size_t)blockIdx.z * FD * FD;
    int f0 = blockIdx.x * 32, o0 = blockIdx.y * 32;
    int tx = threadIdx.x & 31, ty = threadIdx.x >> 5;
    #pragma unroll
    for (int i = 0; i < 32; i += 8)
        tile[ty + i][tx] = Wl[(size_t)(f0 + ty + i) * FD + o0 + tx];
    __syncthreads();
    #pragma unroll
    for (int i = 0; i < 32; i += 8)
        Wtl[(size_t)(o0 + ty + i) * FD + f0 + tx] = f2b(tile[tx][ty + i]);
}

// ---------------- fused all-layer conv v4: wave-uniform gather ----------------
// One block per batch, 1024 threads (16 waves). Each wave gathers one node at a
// time: 64 lanes x 2 feats, conflict-free full-row reads, uniform edge loop.
// GEMM: af = Wt rows in regs (m=out), bf = agg rows (n=node). Epilogue packs
// 8B into the agg tile, then coalesced flush to cat.
__global__ __launch_bounds__(1024) void conv_all_k(
    const float* __restrict__ node_feat,      // [TN][FD] fp32
    const unsigned short* __restrict__ Wt,    // [NL*FD][FD] bf16 (out,f)
    const float* __restrict__ bias,           // [NL*FD]
    const int* __restrict__ rp, const int* __restrict__ ci,
    const float* __restrict__ degs,
    unsigned short* __restrict__ cat)         // [TN][DD] bf16
{
    __shared__ unsigned short hW[NN * HPITCH];     // 131,072 B
    __shared__ unsigned short agg[64 * APITCH];    // 17,408 B
    const int tid = threadIdx.x;
    const int g0 = blockIdx.x * NN;
    const int lane = tid & 63, w = tid >> 6;       // 16 waves
    const int lr = lane & 15, lh = lane >> 4;
    const int wm = w >> 2, wn = w & 3;             // 4(out) x 4(node)

    // initial stage: node_feat fp32 -> hW bf16
    #pragma unroll
    for (int i = 0; i < 8; i++) {
        int u = tid + i * 1024;
        int row = u >> 4, cu = u & 15;
        const float4* s4 = (const float4*)(node_feat + (size_t)(g0 + row) * FD + cu * 8);
        float4 x = s4[0], y = s4[1];
        float tmp[8] = {x.x, x.y, x.z, x.w, y.x, y.y, y.z, y.w};
        *(uint4*)&hW[row * HPITCH + cu * 8] = packv8(tmp);
    }

    for (int l = 0; l < NL; l++) {
        // A-fragments: Wt rows (out channels) in regs for the whole layer
        bf16x8 af[2][4];
        #pragma unroll
        for (int mi = 0; mi < 2; mi++)
            #pragma unroll
            for (int ks = 0; ks < 4; ks++)
                af[mi][ks] = *(const bf16x8*)&Wt[((size_t)l * FD + wm * 32 + mi * 16 + lr) * FD + ks * 32 + lh * 8];
        float4 bs[2];
        #pragma unroll
        for (int mi = 0; mi < 2; mi++)
            bs[mi] = *(const float4*)&bias[l * FD + wm * 32 + mi * 16 + lh * 4];

        for (int ch = 0; ch < 8; ch++) {
            const int crow0 = g0 + ch * 64;
            __syncthreads();   // B_A: prev flush done reading agg; hW stable

            // ---- gather: wave-uniform, 4 nodes per wave, 2 feats per lane ----
            #pragma unroll
            for (int q = 0; q < 4; q++) {
                int nl = w * 4 + q;                 // node within chunk
                int n = crow0 + nl;                 // global node
                unsigned int v = *(const unsigned int*)&hW[(ch * 64 + nl) * HPITCH + lane * 2];
                float a0, a1;
                { union { unsigned int u; float f; } lo, hi;
                  lo.u = v << 16; hi.u = v & 0xffff0000u; a0 = lo.f; a1 = hi.f; }
                int rs = rp[n], re = rp[n + 1];
                int j = rs;
                for (; j + 4 <= re; j += 4) {
                    int s0 = ci[j] - g0, s1 = ci[j + 1] - g0;
                    int s2 = ci[j + 2] - g0, s3 = ci[j + 3] - g0;
                    unsigned int u0 = *(const unsigned int*)&hW[s0 * HPITCH + lane * 2];
                    unsigned int u1 = *(const unsigned int*)&hW[s1 * HPITCH + lane * 2];
                    unsigned int u2 = *(const unsigned int*)&hW[s2 * HPITCH + lane * 2];
                    unsigned int u3 = *(const unsigned int*)&hW[s3 * HPITCH + lane * 2];
                    add2(a0, a1, u0); add2(a0, a1, u1);
                    add2(a0, a1, u2); add2(a0, a1, u3);
                }
                for (; j < re; j++) {
                    int s0 = ci[j] - g0;
                    add2(a0, a1, *(const unsigned int*)&hW[s0 * HPITCH + lane * 2]);
                }
                unsigned int pk = (unsigned int)f2b(a0) | ((unsigned int)f2b(a1) << 16);
                *(unsigned int*)&agg[nl * APITCH + lane * 2] = pk;
            }
            __syncthreads();   // B_B: agg ready

            // ---- MFMA: m=out 128 (wm,mi), n=node 64 (wn,lr), K=128 ----
            f32x4 c0 = (f32x4){0.f, 0.f, 0.f, 0.f};
            f32x4 c1 = (f32x4){0.f, 0.f, 0.f, 0.f};
            {
                const unsigned short* abase = &agg[(wn * 16 + lr) * APITCH + lh * 8];
                #pragma unroll
                for (int ks = 0; ks < 4; ks++) {
                    bf16x8 bfv = *(const bf16x8*)&abase[ks * 32];
                    c0 = __builtin_amdgcn_mfma_f32_16x16x32_bf16(af[0][ks], bfv, c0, 0, 0, 0);
                    c1 = __builtin_amdgcn_mfma_f32_16x16x32_bf16(af[1][ks], bfv, c1, 0, 0, 0);
                }
            }
            __syncthreads();   // B_C: all mfma reads of agg done

            // ---- epilogue: tanh((lin+b)*rdeg), pack 4 ch -> 8B into agg tile ----
            {
                float rd = __builtin_amdgcn_rcpf(degs[crow0 + wn * 16 + lr]);
                float t0 = ftanh((c0[0] + bs[0].x) * rd);
                float t1 = ftanh((c0[1] + bs[0].y) * rd);
                float t2 = ftanh((c0[2] + bs[0].z) * rd);
                float t3 = ftanh((c0[3] + bs[0].w) * rd);
                uint2 p0;
                p0.x = (unsigned int)f2b(t0) | ((unsigned int)f2b(t1) << 16);
                p0.y = (unsigned int)f2b(t2) | ((unsigned int)f2b(t3) << 16);
                *(uint2*)&agg[(wn * 16 + lr) * APITCH + wm * 32 + lh * 4] = p0;
                t0 = ftanh((c1[0] + bs[1].x) * rd);
                t1 = ftanh((c1[1] + bs[1].y) * rd);
                t2 = ftanh((c1[2] + bs[1].z) * rd);
                t3 = ftanh((c1[3] + bs[1].w) * rd);
                uint2 p1;
                p1.x = (unsigned int)f2b(t0) | ((unsigned int)f2b(t1) << 16);
                p1.y = (unsigned int)f2b(t2) | ((unsigned int)f2b(t3) << 16);
                *(uint2*)&agg[(wn * 16 + lr) * APITCH + wm * 32 + 16 + lh * 4] = p1;
            }
            __syncthreads();   // B_D: out-tile ready

            // ---- flush: coalesced 16B stores to cat ----
            {
                int row = tid >> 4, u = tid & 15;
                uint4 v = *(const uint4*)&agg[row * APITCH + u * 8];
                *(uint4*)&cat[(size_t)(crow0 + row) * DD + l * FD + u * 8] = v;
            }
        }

        if (l < NL - 1) {
            __syncthreads();   // flush stores drained (vmcnt0 before barrier)
            #pragma unroll
            for (int i = 0; i < 8; i++) {
                int u = tid + i * 1024;
                int row = u >> 4, cu = u & 15;
                uint4 v = *(const uint4*)&cat[(size_t)(g0 + row) * DD + l * FD + cu * 8];
                *(uint4*)&hW[row * HPITCH + cu * 8] = v;
            }
        }
    }
}

// ---------------- attention scores: bf16 MFMA GEMM + fused tanh/dot-v ----------------
// 1D grid 4096, XCD-swizzled so the 4 n-tiles sharing an X-tile stay on one XCD.
__global__ __launch_bounds__(256) void scores_k(
    const unsigned short* __restrict__ X,   // [TN][DD] bf16
    const unsigned short* __restrict__ Wt,  // [DD][DD] bf16, (n,k)
    const float* __restrict__ bv, const float* __restrict__ vv,
    float* __restrict__ sp)                 // [TN][8] partials
{
    __shared__ unsigned short sX[128][72];
    __shared__ unsigned short sW[128][72];
    int bid = blockIdx.x;
    int swz = (bid & 7) * 512 + (bid >> 3);   // 4096 blocks, 8 XCDs
    int bx = swz >> 2, by = swz & 3;
    int tid = threadIdx.x;
    int lane = tid & 63, wid = tid >> 6;
    int wm = wid >> 1, wn = wid & 1;
    int m0 = bx * 128;
    int n0 = by * 128;
    int lr = lane & 15, lh = lane >> 4;

    f32x4 acc[4][4];
    #pragma unroll
    for (int mi = 0; mi < 4; mi++)
        #pragma unroll
        for (int ni = 0; ni < 4; ni++)
            acc[mi][ni] = (f32x4){0.f, 0.f, 0.f, 0.f};

    for (int k0 = 0; k0 < DD; k0 += 64) {
        __syncthreads();
        #pragma unroll
        for (int i = 0; i < 4; i++) {
            int idx = tid + i * 256;
            int row = idx >> 3, ch = idx & 7;
            *(float4*)&sX[row][ch * 8] = *(const float4*)&X[(size_t)(m0 + row) * DD + k0 + ch * 8];
            *(float4*)&sW[row][ch * 8] = *(const float4*)&Wt[(size_t)(n0 + row) * DD + k0 + ch * 8];
        }
        __syncthreads();
        #pragma unroll
        for (int kk = 0; kk < 64; kk += 32) {
            bf16x8 af[4], bfr[4];
            #pragma unroll
            for (int mi = 0; mi < 4; mi++)
                af[mi] = *(const bf16x8*)&sX[wm * 64 + mi * 16 + lr][kk + lh * 8];
            #pragma unroll
            for (int ni = 0; ni < 4; ni++)
                bfr[ni] = *(const bf16x8*)&sW[wn * 64 + ni * 16 + lr][kk + lh * 8];
            #pragma unroll
            for (int mi = 0; mi < 4; mi++)
                #pragma unroll
                for (int ni = 0; ni < 4; ni++)
                    acc[mi][ni] = __builtin_amdgcn_mfma_f32_16x16x32_bf16(
                        af[mi], bfr[ni], acc[mi][ni], 0, 0, 0);
        }
    }

    float vcol[4], bcol[4];
    #pragma unroll
    for (int ni = 0; ni < 4; ni++) {
        int col = n0 + wn * 64 + ni * 16 + lr;
        vcol[ni] = vv[col];
        bcol[ni] = bv[col];
    }
    #pragma unroll
    for (int mi = 0; mi < 4; mi++) {
        #pragma unroll
        for (int r = 0; r < 4; r++) {
            float part = 0.f;
            #pragma unroll
            for (int ni = 0; ni < 4; ni++)
                part += ftanh(acc[mi][ni][r] + bcol[ni]) * vcol[ni];
            part += __shfl_xor(part, 1);
            part += __shfl_xor(part, 2);
            part += __shfl_xor(part, 4);
            part += __shfl_xor(part, 8);
            if (lr == 0) {
                int row = m0 + wm * 64 + mi * 16 + lh * 4 + r;
                sp[(size_t)row * 8 + by * 2 + wn] = part;
            }
        }
    }
}

// ---------------- softmax + pool (one block per batch) ----------------
__global__ __launch_bounds__(256) void pool_k(
    const float* __restrict__ sp, const unsigned short* __restrict__ X,
    float* __restrict__ pooled)
{
    __shared__ float sattn[512];
    __shared__ float wred[8];
    int b = blockIdx.x, t = threadIdx.x;
    float s0, s1;
    {
        const float4* p = (const float4*)&sp[((size_t)b * NN + t) * 8];
        float4 x = p[0], y = p[1];
        s0 = x.x + x.y + x.z + x.w + y.x + y.y + y.z + y.w;
        p = (const float4*)&sp[((size_t)b * NN + 256 + t) * 8];
        x = p[0]; y = p[1];
        s1 = x.x + x.y + x.z + x.w + y.x + y.y + y.z + y.w;
    }
    float m = fmaxf(s0, s1);
    #pragma unroll
    for (int off = 1; off < 64; off <<= 1) m = fmaxf(m, __shfl_xor(m, off));
    int wid = t >> 6, lane = t & 63;
    if (lane == 0) wred[wid] = m;
    __syncthreads();
    m = fmaxf(fmaxf(wred[0], wred[1]), fmaxf(wred[2], wred[3]));
    float e0 = expf(s0 - m), e1 = expf(s1 - m);
    float ssum = e0 + e1;
    #pragma unroll
    for (int off = 1; off < 64; off <<= 1) ssum += __shfl_xor(ssum, off);
    if (lane == 0) wred[4 + wid] = ssum;
    __syncthreads();
    float inv = 1.0f / (wred[4] + wred[5] + wred[6] + wred[7]);
    sattn[t] = e0 * inv;
    sattn[t + 256] = e1 * inv;
    __syncthreads();
    float2 acc = {0.f, 0.f};
    const unsigned short* Xb = X + (size_t)b * NN * DD;
    #pragma unroll 4
    for (int n = 0; n < NN; n++) {
        float a = sattn[n];
        unsigned int px = *(const unsigned int*)&Xb[(size_t)n * DD + t * 2];
        acc.x += a * b2f(px & 0xffff);
        acc.y += a * b2f(px >> 16);
    }
    pooled[b * DD + t * 2 + 0] = acc.x;
    pooled[b * DD + t * 2 + 1] = acc.y;
}

// ---------------- output layer ----------------
__global__ void out_k(const float* __restrict__ pooled, const float* __restrict__ Wo,
                      const float* __restrict__ bo, float* __restrict__ out) {
    int b = blockIdx.x, c = threadIdx.x;  // 128 threads
    float acc = 0.f;
    const float* p = pooled + b * DD;
    for (int k = 0; k < DD; k++) acc += p[k] * Wo[k * 128 + c];
    out[b * 128 + c] = fmaxf(acc + bo[c], 0.f);
}

extern "C" void kernel_launch(void* const* d_in, const int* in_sizes, int n_in,
                              void* d_out, int out_size, void* d_ws, size_t ws_size,
                              hipStream_t stream)
{
    const float* node_feat = (const float*)d_in[0];
    const int*   edge_src  = (const int*)d_in[1];
    const int*   edge_dst  = (const int*)d_in[2];
    const float* conv_W    = (const float*)d_in[3];
    const float* conv_b    = (const float*)d_in[4];
    const float* att_W     = (const float*)d_in[5];
    const float* att_b     = (const float*)d_in[6];
    const float* att_v     = (const float*)d_in[7];
    const float* out_W     = (const float*)d_in[8];
    const float* out_b     = (const float*)d_in[9];
    float* out = (float*)d_out;
    (void)in_sizes; (void)n_in; (void)out_size;

    char* ws = (char*)d_ws;
    size_t off = 0;
    auto alloc = [&](size_t bytes) {
        void* p = ws + off;
        off += (bytes + 255) & ~(size_t)255;
        return p;
    };
    unsigned short* cat   = (unsigned short*)alloc((size_t)TN * DD * 2);  // bf16
    int*   counts  = (int*)alloc((size_t)TN * 4);
    int*   row_ptr = (int*)alloc((size_t)(TN + 1) * 4);
    int*   cursor  = (int*)alloc((size_t)TN * 4);
    int*   col_idx = (int*)alloc((size_t)NE * 4);
    float* degs    = (float*)alloc((size_t)TN * 4);
    float* sp      = (float*)alloc((size_t)TN * 8 * 4);
    unsigned short* attWt = (unsigned short*)alloc((size_t)DD * DD * 2);  // bf16
    unsigned short* convWt = (unsigned short*)alloc((size_t)NL * FD * FD * 2);
    float* pooled  = (float*)alloc((size_t)NB * DD * 4);
    if (off > ws_size) return;  // diagnostic guard

    hipMemsetAsync(counts, 0, (size_t)TN * 4, stream);
    count_k<<<NE / 256, 256, 0, stream>>>(edge_dst, counts);
    scan_b_k<<<NB, 512, 0, stream>>>(counts, row_ptr, cursor, degs);
    fill_k<<<NE / 256, 256, 0, stream>>>(edge_src, edge_dst, cursor, col_idx);
    transpose_cast_k<<<dim3(DD / 32, DD / 32), 256, 0, stream>>>(att_W, attWt);
    transp_convW_k<<<dim3(FD / 32, FD / 32, NL), 256, 0, stream>>>(conv_W, convWt);

    conv_all_k<<<NB, 1024, 0, stream>>>(node_feat, convWt, conv_b,
                                        row_ptr, col_idx, degs, cat);

    scores_k<<<4096, 256, 0, stream>>>(cat, attWt, att_b, att_v, sp);
    pool_k<<<NB, 256, 0, stream>>>(sp, cat, pooled);
    out_k<<<NB, 128, 0, stream>>>(pooled, out_W, out_b, out);
}

// Round 8
// 499.540 us; speedup vs baseline: 1.0736x; 1.0736x over previous
//
#include <hip/hip_runtime.h>
#include <hip/hip_bf16.h>

#define TN 131072      // total nodes (B*N)
#define NB 256         // batches
#define NN 512         // nodes per batch
#define FD 128         // per-layer feature dim
#define DD 512         // concat dim
#define NE 2097152     // edges
#define NL 4           // layers
#define PITCH 136      // LDS row pitch in bf16 units (272 B; bank stride 4 -> ~2-way)
#define CHK 32         // dst nodes per chunk (double-buffered agg)

typedef __attribute__((ext_vector_type(8))) short bf16x8;
typedef __attribute__((ext_vector_type(4))) float f32x4;

__device__ __forceinline__ float b2f(unsigned int u) {
    union { unsigned int i; float f; } c; c.i = u << 16; return c.f;
}
__device__ __forceinline__ unsigned short f2b(float f) {
    union { float f; unsigned int i; } c; c.f = f;
    unsigned int x = c.i;
    return (unsigned short)((x + 0x7fffu + ((x >> 16) & 1u)) >> 16);  // RNE
}
__device__ __forceinline__ void add2(float& a0, float& a1, unsigned int v) {
    union { unsigned int u; float f; } lo, hi;
    lo.u = v << 16; hi.u = v & 0xffff0000u;
    a0 += lo.f; a1 += hi.f;
}
__device__ __forceinline__ void set2(float& a0, float& a1, unsigned int v) {
    union { unsigned int u; float f; } lo, hi;
    lo.u = v << 16; hi.u = v & 0xffff0000u;
    a0 = lo.f; a1 = hi.f;
}
__device__ __forceinline__ uint4 packv8(const float* a) {
    uint4 p;
    p.x = (unsigned int)f2b(a[0]) | ((unsigned int)f2b(a[1]) << 16);
    p.y = (unsigned int)f2b(a[2]) | ((unsigned int)f2b(a[3]) << 16);
    p.z = (unsigned int)f2b(a[4]) | ((unsigned int)f2b(a[5]) << 16);
    p.w = (unsigned int)f2b(a[6]) | ((unsigned int)f2b(a[7]) << 16);
    return p;
}
// fast tanh: (e^{2x}-1)/(e^{2x}+1), clamped (bf16-exact saturation)
__device__ __forceinline__ float ftanh(float x) {
    float xc = fminf(fmaxf(x, -9.0f), 9.0f);
    float e = __expf(2.0f * xc);
    return (e - 1.0f) * __builtin_amdgcn_rcpf(e + 1.0f);
}

// ---------------- CSR build ----------------
__global__ void count_k(const int* __restrict__ dst, int* __restrict__ counts) {
    int e = blockIdx.x * blockDim.x + threadIdx.x;
    if (e < NE) atomicAdd(&counts[dst[e]], 1);
}

__global__ __launch_bounds__(512) void scan_b_k(const int* __restrict__ counts,
                                                int* __restrict__ row_ptr,
                                                int* __restrict__ cursor,
                                                float* __restrict__ degs) {
    __shared__ int ss[512];
    int b = blockIdx.x, t = threadIdx.x;
    int gid = b * NN + t;
    int c = counts[gid];
    ss[t] = c;
    __syncthreads();
    for (int off = 1; off < 512; off <<= 1) {
        int v = (t >= off) ? ss[t - off] : 0;
        __syncthreads();
        ss[t] += v;
        __syncthreads();
    }
    int excl = ss[t] - c;
    int base = b * (NN * 16) + excl;   // DEG=16
    row_ptr[gid] = base;
    cursor[gid]  = base;
    degs[gid]    = (float)(c + 1);
    if (b == NB - 1 && t == NN - 1) row_ptr[TN] = NE;
}

__global__ void fill_k(const int* __restrict__ src, const int* __restrict__ dst,
                       int* __restrict__ cursor, int* __restrict__ col_idx) {
    int e = blockIdx.x * blockDim.x + threadIdx.x;
    if (e < NE) {
        int p = atomicAdd(&cursor[dst[e]], 1);
        col_idx[p] = src[e];
    }
}

// ---------------- att_W transpose + bf16 cast:  Wt[n][k] = bf16(W[k][n]) ----------------
__global__ __launch_bounds__(256) void transpose_cast_k(const float* __restrict__ W,
                                                        unsigned short* __restrict__ Wt) {
    __shared__ float tile[32][33];
    int k0 = blockIdx.x * 32, n0 = blockIdx.y * 32;
    int tx = threadIdx.x & 31, ty = threadIdx.x >> 5;  // 32 x 8
    #pragma unroll
    for (int i = 0; i < 32; i += 8)
        tile[ty + i][tx] = W[(size_t)(k0 + ty + i) * DD + n0 + tx];
    __syncthreads();
    #pragma unroll
    for (int i = 0; i < 32; i += 8)
        Wt[(size_t)(n0 + ty + i) * DD + k0 + tx] = f2b(tile[tx][ty + i]);
}

// ---------------- conv_W transpose + bf16 cast per layer: Wt_l[o][f] = bf16(W_l[f][o]) ----
__global__ __launch_bounds__(256) void transp_convW_k(const float* __restrict__ W,
                                                      unsigned short* __restrict__ Wt) {
    __shared__ float tile[32][33];
    const float* Wl = W + (size_t)blockIdx.z * FD * FD;
    unsigned short* Wtl = Wt + (size_t)blockIdx.z * FD * FD;
    int f0 = blockIdx.x * 32, o0 = blockIdx.y * 32;
    int tx = threadIdx.x & 31, ty = threadIdx.x >> 5;
    #pragma unroll
    for (int i = 0; i < 32; i += 8)
        tile[ty + i][tx] = Wl[(size_t)(f0 + ty + i) * FD + o0 + tx];
    __syncthreads();
    #pragma unroll
    for (int i = 0; i < 32; i += 8)
        Wtl[(size_t)(o0 + ty + i) * FD + f0 + tx] = f2b(tile[tx][ty + i]);
}

// ---------------- fused all-layer conv v5: dbuf agg, 1 barrier/chunk ----------------
// One block per batch, 1024 threads (16 waves). hW window in LDS (pitch-136).
// Chunk = 32 dst nodes, agg double-buffered. Per chunk bracket:
//   [MFMA(c)+epilogue from agg[cur]  ->  gather(c+1) into agg[cur^1]] -> barrier
// Gather: wave-uniform, half-wave per node (32 lanes x 8B), 4-unrolled ci prefetch.
// GEMM2: m=out (Wt frags in regs), n=dst (agg B-frags), k=f 128.
__global__ __launch_bounds__(1024) void conv_all_k(
    const float* __restrict__ node_feat,      // [TN][FD] fp32
    const unsigned short* __restrict__ Wt,    // [NL*FD][FD] bf16 (out,f)
    const float* __restrict__ bias,           // [NL*FD]
    const int* __restrict__ rp, const int* __restrict__ ci,
    const float* __restrict__ degs,
    unsigned short* __restrict__ cat)         // [TN][DD] bf16
{
    __shared__ unsigned short hW[NN * PITCH];        // 139,264 B
    __shared__ unsigned short agg[2][CHK * PITCH];   // 2 x 8,704 B
    const int tid = threadIdx.x;
    const int g0 = blockIdx.x * NN;
    const int lane = tid & 63, w = tid >> 6;
    const int lr = lane & 15, lh = lane >> 4;
    const int mo = w >> 1, nd = w & 1;     // mfma: 8(out-tiles) x 2(dst-tiles)
    const int gn = tid >> 5;               // gather: node in chunk (0..31)
    const int gs = tid & 31;               // gather: 8B unit (4 feats) in row

    // initial stage: node_feat fp32 -> hW bf16
    #pragma unroll
    for (int i = 0; i < 8; i++) {
        int u = tid + i * 1024;
        int row = u >> 4, cu = u & 15;
        const float4* s4 = (const float4*)(node_feat + (size_t)(g0 + row) * FD + cu * 8);
        float4 x = s4[0], y = s4[1];
        float tmp[8] = {x.x, x.y, x.z, x.w, y.x, y.y, y.z, y.w};
        *(uint4*)&hW[row * PITCH + cu * 8] = packv8(tmp);
    }
    __syncthreads();

    // gather one chunk's aggregation into buf
    auto gather = [&](int c, unsigned short* buf) {
        int nl = c * CHK + gn;                 // node index within batch
        unsigned int v = *(const unsigned int*)&hW[nl * PITCH + gs * 4];
        unsigned int v2 = *(const unsigned int*)&hW[nl * PITCH + gs * 4 + 2];
        float a0, a1, a2, a3;
        set2(a0, a1, v); set2(a2, a3, v2);
        int gnode = g0 + nl;
        int rs = rp[gnode], re = rp[gnode + 1];
        int j = rs;
        for (; j + 4 <= re; j += 4) {
            int s0 = ci[j] - g0, s1 = ci[j + 1] - g0;
            int s2 = ci[j + 2] - g0, s3 = ci[j + 3] - g0;
            uint2 u0 = *(const uint2*)&hW[s0 * PITCH + gs * 4];
            uint2 u1 = *(const uint2*)&hW[s1 * PITCH + gs * 4];
            uint2 u2 = *(const uint2*)&hW[s2 * PITCH + gs * 4];
            uint2 u3 = *(const uint2*)&hW[s3 * PITCH + gs * 4];
            add2(a0, a1, u0.x); add2(a2, a3, u0.y);
            add2(a0, a1, u1.x); add2(a2, a3, u1.y);
            add2(a0, a1, u2.x); add2(a2, a3, u2.y);
            add2(a0, a1, u3.x); add2(a2, a3, u3.y);
        }
        for (; j < re; j++) {
            int s0 = ci[j] - g0;
            uint2 u0 = *(const uint2*)&hW[s0 * PITCH + gs * 4];
            add2(a0, a1, u0.x); add2(a2, a3, u0.y);
        }
        uint2 pk;
        pk.x = (unsigned int)f2b(a0) | ((unsigned int)f2b(a1) << 16);
        pk.y = (unsigned int)f2b(a2) | ((unsigned int)f2b(a3) << 16);
        *(uint2*)&buf[gn * PITCH + gs * 4] = pk;
    };

    for (int l = 0; l < NL; l++) {
        // Wt fragments (A operand, m=out) + bias in regs for the whole layer
        bf16x8 af[4];
        #pragma unroll
        for (int ks = 0; ks < 4; ks++)
            af[ks] = *(const bf16x8*)&Wt[((size_t)l * FD + mo * 16 + lr) * FD + ks * 32 + lh * 8];
        float4 bs = *(const float4*)&bias[l * FD + mo * 16 + lh * 4];

        // prologue: gather chunk 0
        gather(0, agg[0]);
        __syncthreads();

        for (int c = 0; c < NN / CHK; c++) {
            int cur = c & 1;
            // ---- MFMA(c): m=out 128, n=dst 32, k=f 128 ----
            f32x4 cc = (f32x4){0.f, 0.f, 0.f, 0.f};
            {
                const unsigned short* ab = &agg[cur][(nd * 16 + lr) * PITCH + lh * 8];
                #pragma unroll
                for (int ks = 0; ks < 4; ks++) {
                    bf16x8 bfv = *(const bf16x8*)&ab[ks * 32];
                    cc = __builtin_amdgcn_mfma_f32_16x16x32_bf16(af[ks], bfv, cc, 0, 0, 0);
                }
            }
            // ---- epilogue: tanh((lin+b)*rdeg) -> cat (8B packed stores) ----
            {
                int dstl = c * CHK + nd * 16 + lr;
                float rd = __builtin_amdgcn_rcpf(degs[g0 + dstl]);
                float t0 = ftanh((cc[0] + bs.x) * rd);
                float t1 = ftanh((cc[1] + bs.y) * rd);
                float t2 = ftanh((cc[2] + bs.z) * rd);
                float t3 = ftanh((cc[3] + bs.w) * rd);
                uint2 pk;
                pk.x = (unsigned int)f2b(t0) | ((unsigned int)f2b(t1) << 16);
                pk.y = (unsigned int)f2b(t2) | ((unsigned int)f2b(t3) << 16);
                *(uint2*)&cat[(size_t)(g0 + dstl) * DD + l * FD + mo * 16 + lh * 4] = pk;
            }
            // ---- gather(c+1) into the other buffer ----
            if (c < NN / CHK - 1) gather(c + 1, agg[cur ^ 1]);
            __syncthreads();
        }

        // restage hW from this layer's output (L2-hot cat)
        if (l < NL - 1) {
            #pragma unroll
            for (int i = 0; i < 8; i++) {
                int u = tid + i * 1024;
                int row = u >> 4, cu = u & 15;
                uint4 v = *(const uint4*)&cat[(size_t)(g0 + row) * DD + l * FD + cu * 8];
                *(uint4*)&hW[row * PITCH + cu * 8] = v;
            }
            __syncthreads();
        }
    }
}

// ---------------- attention scores: bf16 MFMA GEMM + fused tanh/dot-v ----------------
// 1D grid 4096, XCD-swizzled so each XCD sweeps a contiguous m-range.
__global__ __launch_bounds__(256) void scores_k(
    const unsigned short* __restrict__ X,   // [TN][DD] bf16
    const unsigned short* __restrict__ Wt,  // [DD][DD] bf16, (n,k)
    const float* __restrict__ bv, const float* __restrict__ vv,
    float* __restrict__ sp)                 // [TN][8] partials
{
    __shared__ unsigned short sX[128][72];
    __shared__ unsigned short sW[128][72];
    int bid = blockIdx.x;
    int swz = (bid & 7) * 512 + (bid >> 3);   // 4096 blocks, 8 XCDs
    int bx = swz >> 2, by = swz & 3;
    int tid = threadIdx.x;
    int lane = tid & 63, wid = tid >> 6;
    int wm = wid >> 1, wn = wid & 1;
    int m0 = bx * 128;
    int n0 = by * 128;
    int lr = lane & 15, lh = lane >> 4;

    f32x4 acc[4][4];
    #pragma unroll
    for (int mi = 0; mi < 4; mi++)
        #pragma unroll
        for (int ni = 0; ni < 4; ni++)
            acc[mi][ni] = (f32x4){0.f, 0.f, 0.f, 0.f};

    for (int k0 = 0; k0 < DD; k0 += 64) {
        __syncthreads();
        #pragma unroll
        for (int i = 0; i < 4; i++) {
            int idx = tid + i * 256;
            int row = idx >> 3, ch = idx & 7;
            *(float4*)&sX[row][ch * 8] = *(const float4*)&X[(size_t)(m0 + row) * DD + k0 + ch * 8];
            *(float4*)&sW[row][ch * 8] = *(const float4*)&Wt[(size_t)(n0 + row) * DD + k0 + ch * 8];
        }
        __syncthreads();
        #pragma unroll
        for (int kk = 0; kk < 64; kk += 32) {
            bf16x8 af[4], bfr[4];
            #pragma unroll
            for (int mi = 0; mi < 4; mi++)
                af[mi] = *(const bf16x8*)&sX[wm * 64 + mi * 16 + lr][kk + lh * 8];
            #pragma unroll
            for (int ni = 0; ni < 4; ni++)
                bfr[ni] = *(const bf16x8*)&sW[wn * 64 + ni * 16 + lr][kk + lh * 8];
            #pragma unroll
            for (int mi = 0; mi < 4; mi++)
                #pragma unroll
                for (int ni = 0; ni < 4; ni++)
                    acc[mi][ni] = __builtin_amdgcn_mfma_f32_16x16x32_bf16(
                        af[mi], bfr[ni], acc[mi][ni], 0, 0, 0);
        }
    }

    float vcol[4], bcol[4];
    #pragma unroll
    for (int ni = 0; ni < 4; ni++) {
        int col = n0 + wn * 64 + ni * 16 + lr;
        vcol[ni] = vv[col];
        bcol[ni] = bv[col];
    }
    #pragma unroll
    for (int mi = 0; mi < 4; mi++) {
        #pragma unroll
        for (int r = 0; r < 4; r++) {
            float part = 0.f;
            #pragma unroll
            for (int ni = 0; ni < 4; ni++)
                part += ftanh(acc[mi][ni][r] + bcol[ni]) * vcol[ni];
            part += __shfl_xor(part, 1);
            part += __shfl_xor(part, 2);
            part += __shfl_xor(part, 4);
            part += __shfl_xor(part, 8);
            if (lr == 0) {
                int row = m0 + wm * 64 + mi * 16 + lh * 4 + r;
                sp[(size_t)row * 8 + by * 2 + wn] = part;
            }
        }
    }
}

// ---------------- softmax + pool (one block per batch) ----------------
__global__ __launch_bounds__(256) void pool_k(
    const float* __restrict__ sp, const unsigned short* __restrict__ X,
    float* __restrict__ pooled)
{
    __shared__ float sattn[512];
    __shared__ float wred[8];
    int b = blockIdx.x, t = threadIdx.x;
    float s0, s1;
    {
        const float4* p = (const float4*)&sp[((size_t)b * NN + t) * 8];
        float4 x = p[0], y = p[1];
        s0 = x.x + x.y + x.z + x.w + y.x + y.y + y.z + y.w;
        p = (const float4*)&sp[((size_t)b * NN + 256 + t) * 8];
        x = p[0]; y = p[1];
        s1 = x.x + x.y + x.z + x.w + y.x + y.y + y.z + y.w;
    }
    float m = fmaxf(s0, s1);
    #pragma unroll
    for (int off = 1; off < 64; off <<= 1) m = fmaxf(m, __shfl_xor(m, off));
    int wid = t >> 6, lane = t & 63;
    if (lane == 0) wred[wid] = m;
    __syncthreads();
    m = fmaxf(fmaxf(wred[0], wred[1]), fmaxf(wred[2], wred[3]));
    float e0 = expf(s0 - m), e1 = expf(s1 - m);
    float ssum = e0 + e1;
    #pragma unroll
    for (int off = 1; off < 64; off <<= 1) ssum += __shfl_xor(ssum, off);
    if (lane == 0) wred[4 + wid] = ssum;
    __syncthreads();
    float inv = 1.0f / (wred[4] + wred[5] + wred[6] + wred[7]);
    sattn[t] = e0 * inv;
    sattn[t + 256] = e1 * inv;
    __syncthreads();
    float2 acc = {0.f, 0.f};
    const unsigned short* Xb = X + (size_t)b * NN * DD;
    #pragma unroll 4
    for (int n = 0; n < NN; n++) {
        float a = sattn[n];
        unsigned int px = *(const unsigned int*)&Xb[(size_t)n * DD + t * 2];
        acc.x += a * b2f(px & 0xffff);
        acc.y += a * b2f(px >> 16);
    }
    pooled[b * DD + t * 2 + 0] = acc.x;
    pooled[b * DD + t * 2 + 1] = acc.y;
}

// ---------------- output layer ----------------
__global__ void out_k(const float* __restrict__ pooled, const float* __restrict__ Wo,
                      const float* __restrict__ bo, float* __restrict__ out) {
    int b = blockIdx.x, c = threadIdx.x;  // 128 threads
    float acc = 0.f;
    const float* p = pooled + b * DD;
    for (int k = 0; k < DD; k++) acc += p[k] * Wo[k * 128 + c];
    out[b * 128 + c] = fmaxf(acc + bo[c], 0.f);
}

extern "C" void kernel_launch(void* const* d_in, const int* in_sizes, int n_in,
                              void* d_out, int out_size, void* d_ws, size_t ws_size,
                              hipStream_t stream)
{
    const float* node_feat = (const float*)d_in[0];
    const int*   edge_src  = (const int*)d_in[1];
    const int*   edge_dst  = (const int*)d_in[2];
    const float* conv_W    = (const float*)d_in[3];
    const float* conv_b    = (const float*)d_in[4];
    const float* att_W     = (const float*)d_in[5];
    const float* att_b     = (const float*)d_in[6];
    const float* att_v     = (const float*)d_in[7];
    const float* out_W     = (const float*)d_in[8];
    const float* out_b     = (const float*)d_in[9];
    float* out = (float*)d_out;
    (void)in_sizes; (void)n_in; (void)out_size;

    char* ws = (char*)d_ws;
    size_t off = 0;
    auto alloc = [&](size_t bytes) {
        void* p = ws + off;
        off += (bytes + 255) & ~(size_t)255;
        return p;
    };
    unsigned short* cat   = (unsigned short*)alloc((size_t)TN * DD * 2);  // bf16
    int*   counts  = (int*)alloc((size_t)TN * 4);
    int*   row_ptr = (int*)alloc((size_t)(TN + 1) * 4);
    int*   cursor  = (int*)alloc((size_t)TN * 4);
    int*   col_idx = (int*)alloc((size_t)NE * 4);
    float* degs    = (float*)alloc((size_t)TN * 4);
    float* sp      = (float*)alloc((size_t)TN * 8 * 4);
    unsigned short* attWt = (unsigned short*)alloc((size_t)DD * DD * 2);  // bf16
    unsigned short* convWt = (unsigned short*)alloc((size_t)NL * FD * FD * 2);
    float* pooled  = (float*)alloc((size_t)NB * DD * 4);
    if (off > ws_size) return;  // diagnostic guard

    hipMemsetAsync(counts, 0, (size_t)TN * 4, stream);
    count_k<<<NE / 256, 256, 0, stream>>>(edge_dst, counts);
    scan_b_k<<<NB, 512, 0, stream>>>(counts, row_ptr, cursor, degs);
    fill_k<<<NE / 256, 256, 0, stream>>>(edge_src, edge_dst, cursor, col_idx);
    transpose_cast_k<<<dim3(DD / 32, DD / 32), 256, 0, stream>>>(att_W, attWt);
    transp_convW_k<<<dim3(FD / 32, FD / 32, NL), 256, 0, stream>>>(conv_W, convWt);

    conv_all_k<<<NB, 1024, 0, stream>>>(node_feat, convWt, conv_b,
                                        row_ptr, col_idx, degs, cat);

    scores_k<<<4096, 256, 0, stream>>>(cat, attWt, att_b, att_v, sp);
    pool_k<<<NB, 256, 0, stream>>>(sp, cat, pooled);
    out_k<<<NB, 128, 0, stream>>>(pooled, out_W, out_b, out);
}